// Round 1
// 963.675 us; speedup vs baseline: 1.0532x; 1.0532x over previous
//
#include <hip/hip_runtime.h>

typedef unsigned short u16;
typedef __attribute__((ext_vector_type(8))) short bf16x8;
typedef __attribute__((ext_vector_type(8))) unsigned short u16x8;
typedef __attribute__((ext_vector_type(4))) float f32x4;

#define NTOK 8192
#define DDIM 1024
#define HDIM 4096
#define NEXP 8

typedef __attribute__((address_space(1))) const void gvoid;
typedef __attribute__((address_space(3))) void lvoid;

__device__ __forceinline__ u16 f2b(float f) {
  unsigned u = __float_as_uint(f);
  u += 0x7fffu + ((u >> 16) & 1u);   // RNE
  return (u16)(u >> 16);
}
__device__ __forceinline__ void glds16(const void* g, void* l) {
  __builtin_amdgcn_global_load_lds((gvoid*)g, (lvoid*)l, 16, 0, 0);
}

// ---------------- pre-pass: x fp32 -> bf16 ----------------------------------
__global__ void convert_x_kernel(const float* __restrict__ src, u16* __restrict__ dst) {
  size_t i = ((size_t)blockIdx.x * 256 + threadIdx.x) * 8;
  float4 a = *(const float4*)(src + i);
  float4 b = *(const float4*)(src + i + 4);
  u16x8 o;
  o[0] = f2b(a.x); o[1] = f2b(a.y); o[2] = f2b(a.z); o[3] = f2b(a.w);
  o[4] = f2b(b.x); o[5] = f2b(b.y); o[6] = f2b(b.z); o[7] = f2b(b.w);
  *(u16x8*)(dst + i) = o;
}

// ---------------- pre-pass: [R][C] fp32 -> [C][R] bf16 (per expert) ---------
__global__ void transpose_kernel(const float* __restrict__ src, u16* __restrict__ dst,
                                 int R, int C) {
  int e = blockIdx.z;
  src += (size_t)e * R * C;
  dst += (size_t)e * R * C;
  int r0 = blockIdx.y * 64, c0 = blockIdx.x * 64;
  __shared__ u16 T[64][68];   // row stride 136 B: 8B-aligned, 2-way bank alias (free)
  int t = threadIdx.x;
  int rr = t >> 4, cc = (t & 15) * 4;
#pragma unroll
  for (int i = 0; i < 4; ++i) {
    int r = i * 16 + rr;
    float4 v = *(const float4*)(src + (size_t)(r0 + r) * C + c0 + cc);
    T[cc + 0][r] = f2b(v.x);
    T[cc + 1][r] = f2b(v.y);
    T[cc + 2][r] = f2b(v.z);
    T[cc + 3][r] = f2b(v.w);
  }
  __syncthreads();
#pragma unroll
  for (int i = 0; i < 4; ++i) {
    int c = i * 16 + rr;
    ushort4 o = *(const ushort4*)&T[c][cc];
    *(ushort4*)(dst + (size_t)(c0 + c) * R + r0 + cc) = o;
  }
}

// ---------------- gating: softmax over 8 experts, top-2, bucket by expert ----
__global__ void gate_kernel(const float* __restrict__ x, const float* __restrict__ Wg,
                            const float* __restrict__ bg, int* __restrict__ counts,
                            int* __restrict__ pair_tok, float* __restrict__ pair_w,
                            int* __restrict__ tok_ep)
{
  int lane = threadIdx.x & 63;
  int wave = threadIdx.x >> 6;
  int tok = blockIdx.x * 4 + wave;
  const float* xr = x + (size_t)tok * DDIM + lane * 16;
  float acc[NEXP];
#pragma unroll
  for (int e = 0; e < NEXP; ++e) acc[e] = 0.f;
#pragma unroll
  for (int j = 0; j < 16; ++j) {
    float xf = xr[j];
    const float* wr = Wg + (size_t)(lane * 16 + j) * NEXP;
    float4 wa = *(const float4*)(wr);
    float4 wb = *(const float4*)(wr + 4);
    acc[0] = fmaf(xf, wa.x, acc[0]);
    acc[1] = fmaf(xf, wa.y, acc[1]);
    acc[2] = fmaf(xf, wa.z, acc[2]);
    acc[3] = fmaf(xf, wa.w, acc[3]);
    acc[4] = fmaf(xf, wb.x, acc[4]);
    acc[5] = fmaf(xf, wb.y, acc[5]);
    acc[6] = fmaf(xf, wb.z, acc[6]);
    acc[7] = fmaf(xf, wb.w, acc[7]);
  }
#pragma unroll
  for (int off = 32; off > 0; off >>= 1) {
#pragma unroll
    for (int e = 0; e < NEXP; ++e) acc[e] += __shfl_xor(acc[e], off, 64);
  }
  if (lane == 0) {
    float l[NEXP];
    float mx = -3.4e38f;
#pragma unroll
    for (int e = 0; e < NEXP; ++e) { l[e] = acc[e] + bg[e]; mx = fmaxf(mx, l[e]); }
    float s = 0.f;
#pragma unroll
    for (int e = 0; e < NEXP; ++e) { l[e] = __expf(l[e] - mx); s += l[e]; }
    float inv = 1.f / s;
    float v1 = -1.f; int i1 = 0;
#pragma unroll
    for (int e = 0; e < NEXP; ++e) { if (l[e] > v1) { v1 = l[e]; i1 = e; } }
    float v2 = -1.f; int i2 = 0;
#pragma unroll
    for (int e = 0; e < NEXP; ++e) { if (e != i1 && l[e] > v2) { v2 = l[e]; i2 = e; } }
    int p1 = atomicAdd(&counts[i1], 1);
    pair_tok[i1 * NTOK + p1] = tok;
    pair_w[i1 * NTOK + p1] = v1 * inv;   // raw top-k softmax prob (not renormalized)
    int p2 = atomicAdd(&counts[i2], 1);
    pair_tok[i2 * NTOK + p2] = tok;
    pair_w[i2 * NTOK + p2] = v2 * inv;
    tok_ep[2 * tok + 0] = (i1 << 16) | p1;
    tok_ep[2 * tok + 1] = (i2 << 16) | p2;
  }
}

__global__ void offsets_kernel(const int* __restrict__ counts, int* __restrict__ offsets) {
  if (threadIdx.x == 0) {
    int s = 0;
    for (int e = 0; e < NEXP; ++e) { offsets[e] = s; s += counts[e]; }
  }
}

// ---------------- shared GEMM helpers ---------------------------------------
// stage one 128x32 A tile + 128x32 B tile into LDS buffer (linear layout)
__device__ __forceinline__ void stage4(const u16* xa0, const u16* xa1,
                                       const u16* wb0, const u16* wb1,
                                       u16* Asb, u16* Bsb, int wave, int koff) {
  glds16(xa0 + koff, Asb + wave * 512);
  glds16(xa1 + koff, Asb + 2048 + wave * 512);
  glds16(wb0 + koff, Bsb + wave * 512);
  glds16(wb1 + koff, Bsb + 2048 + wave * 512);
}

// 16 MFMAs for one BK=32 step from LDS buffer
__device__ __forceinline__ void mfma_tile(const u16* Asb, const u16* Bsb,
                                          f32x4 (&acc)[4][4],
                                          int wrr, int wc, int ln, int q) {
  bf16x8 af[4], bfr[4];
#pragma unroll
  for (int mt = 0; mt < 4; ++mt)
    af[mt] = *(const bf16x8*)(Asb + (wrr + mt * 16 + ln) * 32 + q * 8);
#pragma unroll
  for (int nt = 0; nt < 4; ++nt)
    bfr[nt] = *(const bf16x8*)(Bsb + (wc + nt * 16 + ln) * 32 + q * 8);
#pragma unroll
  for (int mt = 0; mt < 4; ++mt)
#pragma unroll
    for (int nt = 0; nt < 4; ++nt)
      acc[mt][nt] = __builtin_amdgcn_mfma_f32_16x16x32_bf16(af[mt], bfr[nt], acc[mt][nt], 0, 0, 0);
}

// ---------------- grouped GEMM1: h = relu(gather(xb) @ W1T[e]^T + b1[e]) ----
// xb: [NTOK][D] bf16; W1T: [E][H][D] bf16 (K-contiguous rows)
// grid: (hp/128 cols, NEXP, 64 row-tiles)  -> early-return blocks dispatch last
__global__ __launch_bounds__(256) void gemm1_kernel(
    const u16* __restrict__ xb, const u16* __restrict__ W1T,
    const float* __restrict__ b1, const int* __restrict__ counts,
    const int* __restrict__ offsets, const int* __restrict__ pair_tok,
    u16* __restrict__ h, int hp, int p0)
{
  int e = blockIdx.y;
  int cnt = counts[e];
  int i0 = blockIdx.z * 128;
  if (i0 >= cnt) return;
  int n0 = blockIdx.x * 128;               // column offset within this phase

  __shared__ __align__(16) u16 As[2][128 * 32];
  __shared__ __align__(16) u16 Bs[2][128 * 32];

  int t = threadIdx.x;
  int lane = t & 63;
  int wave = t >> 6;
  int rlim = cnt - i0;

  const int* tokp = pair_tok + e * NTOK + i0;
  int arow = t >> 2;
  int c8 = (t & 3) * 8;
  const u16* xa0 = xb + (size_t)tokp[min(arow, rlim - 1)] * DDIM + c8;
  const u16* xa1 = xb + (size_t)tokp[min(arow + 64, rlim - 1)] * DDIM + c8;
  const u16* wb0 = W1T + (size_t)e * HDIM * DDIM + (size_t)(p0 + n0 + arow) * DDIM + c8;
  const u16* wb1 = wb0 + (size_t)64 * DDIM;

  f32x4 acc[4][4] = {};
  int wrr = (wave >> 1) * 64;
  int wc = (wave & 1) * 64;
  int ln = lane & 15;
  int q = lane >> 4;

  // double-buffered 2-phase pipeline: prefetch next BK=32 before computing cur
  stage4(xa0, xa1, wb0, wb1, As[0], Bs[0], wave, 0);
  __syncthreads();                              // vmcnt(0)+barrier: buf0 ready
  for (int k0 = 0; k0 < DDIM; k0 += 64) {
    stage4(xa0, xa1, wb0, wb1, As[1], Bs[1], wave, k0 + 32);
    __builtin_amdgcn_sched_barrier(0);          // keep load-issue ahead of compute
    mfma_tile(As[0], Bs[0], acc, wrr, wc, ln, q);
    __syncthreads();                            // drains buf1 loads; buf0 free
    if (k0 + 64 < DDIM) {
      stage4(xa0, xa1, wb0, wb1, As[0], Bs[0], wave, k0 + 64);
      __builtin_amdgcn_sched_barrier(0);
    }
    mfma_tile(As[1], Bs[1], acc, wrr, wc, ln, q);
    __syncthreads();
  }

  int ob = offsets[e];
  float bb[4];
#pragma unroll
  for (int nt = 0; nt < 4; ++nt)
    bb[nt] = b1[(size_t)e * HDIM + p0 + n0 + wc + nt * 16 + ln];
  size_t hbase = (size_t)(ob + i0) * hp + n0 + wc;
#pragma unroll
  for (int mt = 0; mt < 4; ++mt) {
#pragma unroll
    for (int r = 0; r < 4; ++r) {
      int row = wrr + mt * 16 + q * 4 + r;
      if (row < rlim) {
        u16* hrow = h + hbase + (size_t)row * hp;
#pragma unroll
        for (int nt = 0; nt < 4; ++nt) {
          float v = acc[mt][nt][r] + bb[nt];
          hrow[nt * 16 + ln] = f2b(fmaxf(v, 0.f));
        }
      }
    }
  }
}

// ---------------- grouped GEMM2: y[slot] (+)= h @ W2T[e]^T (+ b2[e]) --------
// h: [rows][hp] bf16; W2T: [E][D][H] bf16 (K-contiguous rows)
// grid: (NEXP, DDIM/128, 64 row-tiles) -> blockIdx.x = expert => XCD affinity
// No atomics: each y element has a unique writer per dispatch.
__global__ __launch_bounds__(256) void gemm2_kernel(
    const u16* __restrict__ h, const u16* __restrict__ W2T,
    const float* __restrict__ b2v, const int* __restrict__ counts,
    const int* __restrict__ offsets, float* __restrict__ y,
    int hp, int p0, int first)
{
  int e = blockIdx.x;
  int cnt = counts[e];
  int i0 = blockIdx.z * 128;
  if (i0 >= cnt) return;
  int n0 = blockIdx.y * 128;

  __shared__ __align__(16) u16 As[2][128 * 32];
  __shared__ __align__(16) u16 Bs[2][128 * 32];

  int t = threadIdx.x;
  int lane = t & 63;
  int wave = t >> 6;
  int rlim = cnt - i0;
  int rbase = offsets[e] + i0;

  int arow = t >> 2;
  int c8 = (t & 3) * 8;
  const u16* xa0 = h + (size_t)(rbase + arow) * hp + c8;
  const u16* xa1 = h + (size_t)(rbase + arow + 64) * hp + c8;
  const u16* wb0 = W2T + (size_t)e * DDIM * HDIM + (size_t)(n0 + arow) * HDIM + p0 + c8;
  const u16* wb1 = wb0 + (size_t)64 * HDIM;

  f32x4 acc[4][4] = {};
  int wrr = (wave >> 1) * 64;
  int wc = (wave & 1) * 64;
  int ln = lane & 15;
  int q = lane >> 4;

  stage4(xa0, xa1, wb0, wb1, As[0], Bs[0], wave, 0);
  __syncthreads();
  for (int k0 = 0; k0 < hp; k0 += 64) {
    stage4(xa0, xa1, wb0, wb1, As[1], Bs[1], wave, k0 + 32);
    __builtin_amdgcn_sched_barrier(0);
    mfma_tile(As[0], Bs[0], acc, wrr, wc, ln, q);
    __syncthreads();
    if (k0 + 64 < hp) {
      stage4(xa0, xa1, wb0, wb1, As[0], Bs[0], wave, k0 + 64);
      __builtin_amdgcn_sched_barrier(0);
    }
    mfma_tile(As[1], Bs[1], acc, wrr, wc, ln, q);
    __syncthreads();
  }

  float bb[4];
#pragma unroll
  for (int nt = 0; nt < 4; ++nt)
    bb[nt] = first ? b2v[(size_t)e * DDIM + n0 + wc + nt * 16 + ln] : 0.f;
#pragma unroll
  for (int mt = 0; mt < 4; ++mt) {
#pragma unroll
    for (int r = 0; r < 4; ++r) {
      int row = wrr + mt * 16 + q * 4 + r;
      if (row < rlim) {
        float* yr = y + (size_t)(rbase + row) * DDIM + n0 + wc;
#pragma unroll
        for (int nt = 0; nt < 4; ++nt) {
          float v = acc[mt][nt][r] + bb[nt];
          if (first) yr[nt * 16 + ln] = v;
          else       yr[nt * 16 + ln] += v;
        }
      }
    }
  }
}

// ---------------- combine: out[tok] = w1*y[slot1] + w2*y[slot2] -------------
__global__ __launch_bounds__(256) void combine_kernel(
    const float* __restrict__ y, const int* __restrict__ tok_ep,
    const float* __restrict__ pair_w, const int* __restrict__ offsets,
    float* __restrict__ out)
{
  int tok = blockIdx.x;
  int ep1 = tok_ep[2 * tok + 0];
  int ep2 = tok_ep[2 * tok + 1];
  int e1 = ep1 >> 16, p1 = ep1 & 0xffff;
  int e2 = ep2 >> 16, p2 = ep2 & 0xffff;
  float w1 = pair_w[e1 * NTOK + p1];
  float w2 = pair_w[e2 * NTOK + p2];
  const float* r1 = y + (size_t)(offsets[e1] + p1) * DDIM;
  const float* r2 = y + (size_t)(offsets[e2] + p2) * DDIM;
  int c = threadIdx.x * 4;
  float4 a = *(const float4*)(r1 + c);
  float4 b = *(const float4*)(r2 + c);
  float4 o;
  o.x = w1 * a.x + w2 * b.x;
  o.y = w1 * a.y + w2 * b.y;
  o.z = w1 * a.z + w2 * b.z;
  o.w = w1 * a.w + w2 * b.w;
  *(float4*)(out + (size_t)tok * DDIM + c) = o;
}

// ---------------- host launch ------------------------------------------------
extern "C" void kernel_launch(void* const* d_in, const int* in_sizes, int n_in,
                              void* d_out, int out_size, void* d_ws, size_t ws_size,
                              hipStream_t stream)
{
  const float* x  = (const float*)d_in[0];
  const float* Wg = (const float*)d_in[1];
  const float* bg = (const float*)d_in[2];
  const float* W1 = (const float*)d_in[3];
  const float* b1 = (const float*)d_in[4];
  const float* W2 = (const float*)d_in[5];
  const float* b2 = (const float*)d_in[6];
  float* out = (float*)d_out;

  char* ws = (char*)d_ws;
  int*   counts   = (int*)(ws + 0);
  int*   offsets  = (int*)(ws + 64);
  int*   tok_ep   = (int*)(ws + 128);                            // 65536 B
  int*   pair_tok = (int*)(ws + 128 + 65536);                    // 262144 B
  float* pair_w   = (float*)(ws + 128 + 65536 + 262144);         // 262144 B
  u16*   xb  = (u16*)(ws + 589952);                              // 16.78 MB
  u16*   W1T = (u16*)(ws + 589952 + 16777216);                   // 67.1 MB
  u16*   W2T = (u16*)(ws + 589952 + 16777216 + 67108864);        // 67.1 MB
  float* yb  = (float*)(ws + 589952 + 16777216 + 2 * (size_t)67108864);  // 67.1 MB
  u16*   hbuf = (u16*)(ws + 589952 + 16777216 + 3 * (size_t)67108864);
  size_t used_base = 589952 + 16777216 + 3 * (size_t)67108864;   // 218693760

  // largest H-phase width whose h buffer ((16384+128) rows x hp bf16) fits in ws
  int hp = 128;
  const int cands[6] = {4096, 2048, 1024, 512, 256, 128};
  for (int ci = 0; ci < 6; ++ci) {
    if (used_base + (size_t)16512 * cands[ci] * 2 <= ws_size) { hp = cands[ci]; break; }
  }

  hipMemsetAsync(counts, 0, 64, stream);
  convert_x_kernel<<<NTOK * DDIM / 2048, 256, 0, stream>>>(x, xb);
  // W1 [E][D][H] -> W1T [E][H][D]
  transpose_kernel<<<dim3(HDIM / 64, DDIM / 64, NEXP), 256, 0, stream>>>(W1, W1T, DDIM, HDIM);
  // W2 [E][H][D] -> W2T [E][D][H]
  transpose_kernel<<<dim3(DDIM / 64, HDIM / 64, NEXP), 256, 0, stream>>>(W2, W2T, HDIM, DDIM);
  gate_kernel<<<NTOK / 4, 256, 0, stream>>>(x, Wg, bg, counts, pair_tok, pair_w, tok_ep);
  offsets_kernel<<<1, 64, 0, stream>>>(counts, offsets);
  for (int p0 = 0; p0 < HDIM; p0 += hp) {
    gemm1_kernel<<<dim3(hp / 128, NEXP, 64), 256, 0, stream>>>(
        xb, W1T, b1, counts, offsets, pair_tok, hbuf, hp, p0);
    gemm2_kernel<<<dim3(NEXP, DDIM / 128, 64), 256, 0, stream>>>(
        hbuf, W2T, b2, counts, offsets, yb, hp, p0, p0 == 0 ? 1 : 0);
  }
  combine_kernel<<<NTOK, 256, 0, stream>>>(yb, tok_ep, pair_w, offsets, out);
}

// Round 2
// 943.738 us; speedup vs baseline: 1.0754x; 1.0211x over previous
//
#include <hip/hip_runtime.h>

typedef unsigned short u16;
typedef __attribute__((ext_vector_type(8))) short bf16x8;
typedef __attribute__((ext_vector_type(8))) unsigned short u16x8;
typedef __attribute__((ext_vector_type(4))) float f32x4;

#define NTOK 8192
#define DDIM 1024
#define HDIM 4096
#define NEXP 8

typedef __attribute__((address_space(1))) const void gvoid;
typedef __attribute__((address_space(3))) void lvoid;

__device__ __forceinline__ u16 f2b(float f) {
  unsigned u = __float_as_uint(f);
  u += 0x7fffu + ((u >> 16) & 1u);   // RNE
  return (u16)(u >> 16);
}
__device__ __forceinline__ void glds16(const void* g, void* l) {
  __builtin_amdgcn_global_load_lds((gvoid*)g, (lvoid*)l, 16, 0, 0);
}

// ---------------- pre-pass: x fp32 -> bf16 ----------------------------------
__global__ void convert_x_kernel(const float* __restrict__ src, u16* __restrict__ dst) {
  size_t i = ((size_t)blockIdx.x * 256 + threadIdx.x) * 8;
  float4 a = *(const float4*)(src + i);
  float4 b = *(const float4*)(src + i + 4);
  u16x8 o;
  o[0] = f2b(a.x); o[1] = f2b(a.y); o[2] = f2b(a.z); o[3] = f2b(a.w);
  o[4] = f2b(b.x); o[5] = f2b(b.y); o[6] = f2b(b.z); o[7] = f2b(b.w);
  *(u16x8*)(dst + i) = o;
}

// ---------------- pre-pass: [R][C] fp32 -> [C][R] bf16 (per expert) ---------
__global__ void transpose_kernel(const float* __restrict__ src, u16* __restrict__ dst,
                                 int R, int C) {
  int e = blockIdx.z;
  src += (size_t)e * R * C;
  dst += (size_t)e * R * C;
  int r0 = blockIdx.y * 64, c0 = blockIdx.x * 64;
  __shared__ u16 T[64][68];
  int t = threadIdx.x;
  int rr = t >> 4, cc = (t & 15) * 4;
#pragma unroll
  for (int i = 0; i < 4; ++i) {
    int r = i * 16 + rr;
    float4 v = *(const float4*)(src + (size_t)(r0 + r) * C + c0 + cc);
    T[cc + 0][r] = f2b(v.x);
    T[cc + 1][r] = f2b(v.y);
    T[cc + 2][r] = f2b(v.z);
    T[cc + 3][r] = f2b(v.w);
  }
  __syncthreads();
#pragma unroll
  for (int i = 0; i < 4; ++i) {
    int c = i * 16 + rr;
    ushort4 o = *(const ushort4*)&T[c][cc];
    *(ushort4*)(dst + (size_t)(c0 + c) * R + r0 + cc) = o;
  }
}

// ---------------- gating: softmax over 8 experts, top-2, bucket by expert ----
__global__ void gate_kernel(const float* __restrict__ x, const float* __restrict__ Wg,
                            const float* __restrict__ bg, int* __restrict__ counts,
                            int* __restrict__ pair_tok, float* __restrict__ pair_w,
                            int* __restrict__ tok_ep)
{
  int lane = threadIdx.x & 63;
  int wave = threadIdx.x >> 6;
  int tok = blockIdx.x * 4 + wave;
  const float* xr = x + (size_t)tok * DDIM + lane * 16;
  float acc[NEXP];
#pragma unroll
  for (int e = 0; e < NEXP; ++e) acc[e] = 0.f;
#pragma unroll
  for (int j = 0; j < 16; ++j) {
    float xf = xr[j];
    const float* wr = Wg + (size_t)(lane * 16 + j) * NEXP;
    float4 wa = *(const float4*)(wr);
    float4 wb = *(const float4*)(wr + 4);
    acc[0] = fmaf(xf, wa.x, acc[0]);
    acc[1] = fmaf(xf, wa.y, acc[1]);
    acc[2] = fmaf(xf, wa.z, acc[2]);
    acc[3] = fmaf(xf, wa.w, acc[3]);
    acc[4] = fmaf(xf, wb.x, acc[4]);
    acc[5] = fmaf(xf, wb.y, acc[5]);
    acc[6] = fmaf(xf, wb.z, acc[6]);
    acc[7] = fmaf(xf, wb.w, acc[7]);
  }
#pragma unroll
  for (int off = 32; off > 0; off >>= 1) {
#pragma unroll
    for (int e = 0; e < NEXP; ++e) acc[e] += __shfl_xor(acc[e], off, 64);
  }
  if (lane == 0) {
    float l[NEXP];
    float mx = -3.4e38f;
#pragma unroll
    for (int e = 0; e < NEXP; ++e) { l[e] = acc[e] + bg[e]; mx = fmaxf(mx, l[e]); }
    float s = 0.f;
#pragma unroll
    for (int e = 0; e < NEXP; ++e) { l[e] = __expf(l[e] - mx); s += l[e]; }
    float inv = 1.f / s;
    float v1 = -1.f; int i1 = 0;
#pragma unroll
    for (int e = 0; e < NEXP; ++e) { if (l[e] > v1) { v1 = l[e]; i1 = e; } }
    float v2 = -1.f; int i2 = 0;
#pragma unroll
    for (int e = 0; e < NEXP; ++e) { if (e != i1 && l[e] > v2) { v2 = l[e]; i2 = e; } }
    int p1 = atomicAdd(&counts[i1], 1);
    pair_tok[i1 * NTOK + p1] = tok;
    pair_w[i1 * NTOK + p1] = v1 * inv;
    int p2 = atomicAdd(&counts[i2], 1);
    pair_tok[i2 * NTOK + p2] = tok;
    pair_w[i2 * NTOK + p2] = v2 * inv;
    tok_ep[2 * tok + 0] = (i1 << 16) | p1;
    tok_ep[2 * tok + 1] = (i2 << 16) | p2;
  }
}

__global__ void offsets_kernel(const int* __restrict__ counts, int* __restrict__ offsets) {
  if (threadIdx.x == 0) {
    int s = 0;
    for (int e = 0; e < NEXP; ++e) { offsets[e] = s; s += counts[e]; }
  }
}

// ---------------- 256x256 / BK=64 / 8-wave / 8-phase grouped GEMM core ------
// LDS (dynamic, 128 KiB): A[2buf][2half][128r][64k] then B same, bf16.
// Writes linear (glds16); reads+global-src use XOR swizzle byte^=((row&7)<<4).
#define MFMA16 __builtin_amdgcn_mfma_f32_16x16x32_bf16

#define MM2(mt, A0, A1) \
  acc[mt][0] = MFMA16(A0, b00, acc[mt][0], 0, 0, 0); \
  acc[mt][1] = MFMA16(A0, b10, acc[mt][1], 0, 0, 0); \
  acc[mt][2] = MFMA16(A0, b20, acc[mt][2], 0, 0, 0); \
  acc[mt][3] = MFMA16(A0, b30, acc[mt][3], 0, 0, 0); \
  acc[mt][0] = MFMA16(A1, b01, acc[mt][0], 0, 0, 0); \
  acc[mt][1] = MFMA16(A1, b11, acc[mt][1], 0, 0, 0); \
  acc[mt][2] = MFMA16(A1, b21, acc[mt][2], 0, 0, 0); \
  acc[mt][3] = MFMA16(A1, b31, acc[mt][3], 0, 0, 0)

#define DSA(mt, ks) (*(const bf16x8*)(Ab + (mt) * 2048 + ((ks) ? qs1 : qs0)))
#define DSB(nt, ks) (*(const bf16x8*)(Bb + (nt) * 2048 + ((ks) ? qs1 : qs0)))

#define BARM() do { __builtin_amdgcn_s_barrier(); asm volatile("" ::: "memory"); } while (0)
#define PH_SYNC() do { __builtin_amdgcn_s_barrier();                        \
  asm volatile("s_waitcnt lgkmcnt(0)" ::: "memory");                        \
  __builtin_amdgcn_sched_barrier(0); } while (0)

#define GEMM_MAINLOOP(NK)                                                    \
  glds16(pA00, dA00); glds16(pA01, dA01);                                    \
  glds16(pA10, dA10); glds16(pA11, dA11);                                    \
  glds16(pB00, dB00); glds16(pB01, dB01);                                    \
  glds16(pB10, dB10); glds16(pB11, dB11);                                    \
  glds16(pA00 + 64, dA00 + 16384); glds16(pA01 + 64, dA01 + 16384);          \
  asm volatile("s_waitcnt vmcnt(2)" ::: "memory");                           \
  BARM();                                                                    \
  for (int k = 0; k < (NK); ++k) {                                           \
    int cur = k & 1, nxt = cur ^ 1;                                          \
    const char* Ab = ldsc + cur * 32768 + abase;                             \
    const char* Bb = ldsc + 65536 + cur * 32768 + bbase;                     \
    int kk = (k + 1) * 64;                                                   \
    bool pf = (k + 1 < (NK));                                                \
    if (pf) { glds16(pA10 + kk, dA10 + nxt * 16384);                         \
              glds16(pA11 + kk, dA11 + nxt * 16384); }                       \
    bf16x8 b00 = DSB(0, 0), b01 = DSB(0, 1), b10 = DSB(1, 0), b11 = DSB(1, 1);\
    bf16x8 b20 = DSB(2, 0), b21 = DSB(2, 1), b30 = DSB(3, 0), b31 = DSB(3, 1);\
    bf16x8 a0 = DSA(0, 0), a1 = DSA(0, 1), a2 = DSA(1, 0), a3 = DSA(1, 1);   \
    PH_SYNC();                                                               \
    __builtin_amdgcn_s_setprio(1); MM2(0, a0, a1); MM2(1, a2, a3);           \
    __builtin_amdgcn_s_setprio(0); BARM();                                   \
    if (pf) { glds16(pB00 + kk, dB00 + nxt * 16384);                         \
              glds16(pB01 + kk, dB01 + nxt * 16384); }                       \
    a0 = DSA(2, 0); a1 = DSA(2, 1); a2 = DSA(3, 0); a3 = DSA(3, 1);          \
    PH_SYNC();                                                               \
    __builtin_amdgcn_s_setprio(1); MM2(2, a0, a1); MM2(3, a2, a3);           \
    __builtin_amdgcn_s_setprio(0); BARM();                                   \
    if (pf) { glds16(pB10 + kk, dB10 + nxt * 16384);                         \
              glds16(pB11 + kk, dB11 + nxt * 16384); }                       \
    a0 = DSA(4, 0); a1 = DSA(4, 1); a2 = DSA(5, 0); a3 = DSA(5, 1);          \
    PH_SYNC();                                                               \
    __builtin_amdgcn_s_setprio(1); MM2(4, a0, a1); MM2(5, a2, a3);           \
    __builtin_amdgcn_s_setprio(0); BARM();                                   \
    a0 = DSA(6, 0); a1 = DSA(6, 1); a2 = DSA(7, 0); a3 = DSA(7, 1);          \
    PH_SYNC();                                                               \
    __builtin_amdgcn_s_setprio(1); MM2(6, a0, a1); MM2(7, a2, a3);           \
    __builtin_amdgcn_s_setprio(0); BARM();                                   \
    if (k + 2 < (NK)) {                                                      \
      glds16(pA00 + kk + 64, dA00 + cur * 16384);                            \
      glds16(pA01 + kk + 64, dA01 + cur * 16384);                            \
      asm volatile("s_waitcnt vmcnt(2)" ::: "memory");                       \
      BARM();                                                                \
    } else if (pf) {                                                         \
      asm volatile("s_waitcnt vmcnt(0)" ::: "memory");                       \
      BARM();                                                                \
    }                                                                        \
  }

// staging thread -> (row, swizzled k-col) within a 128x64 half tile
#define STAGE_MAP()                                                          \
  int t = threadIdx.x;                                                       \
  int wv = t >> 6;                                                           \
  int lane = t & 63;                                                         \
  int ln = lane & 15, q = lane >> 4;                                         \
  int wm = wv >> 2, wn = wv & 3;                                             \
  int o0 = t * 16, o1 = 8192 + t * 16;                                       \
  int r0 = o0 >> 7, r1 = o1 >> 7;                                            \
  int c0 = ((o0 ^ (((o0 >> 7) & 7) << 4)) & 127) >> 1;                       \
  int c1 = ((o1 ^ (((o1 >> 7) & 7) << 4)) & 127) >> 1;                       \
  int sw = (ln & 7) << 4;                                                    \
  int qs0 = (q * 16) ^ sw;                                                   \
  int qs1 = (64 + q * 16) ^ sw;                                              \
  int abase = wm * 16384 + ln * 128;                                         \
  int bbase = (wn >> 1) * 16384 + (wn & 1) * 8192 + ln * 128;                \
  u16* dA00 = lds_u16 + wv * 512;                                            \
  u16* dA01 = lds_u16 + 4096 + wv * 512;                                     \
  u16* dA10 = lds_u16 + 8192 + wv * 512;                                     \
  u16* dA11 = lds_u16 + 12288 + wv * 512;                                    \
  u16* dB00 = lds_u16 + 32768 + wv * 512;                                    \
  u16* dB01 = lds_u16 + 32768 + 4096 + wv * 512;                             \
  u16* dB10 = lds_u16 + 32768 + 8192 + wv * 512;                             \
  u16* dB11 = lds_u16 + 32768 + 12288 + wv * 512;                            \
  const char* ldsc = (const char*)lds_u16;

// ---------------- grouped GEMM1: h = relu(gather(xb) @ W1T[e]^T + b1[e]) ----
__global__ __launch_bounds__(512, 2) void gemm1_kernel(
    const u16* __restrict__ xb, const u16* __restrict__ W1T,
    const float* __restrict__ b1, const int* __restrict__ counts,
    const int* __restrict__ offsets, const int* __restrict__ pair_tok,
    u16* __restrict__ h, int hp, int p0)
{
  int e = blockIdx.x;
  int cnt = counts[e];
  int i0 = blockIdx.z * 256;
  if (i0 >= cnt) return;
  int n0 = blockIdx.y * 256;
  extern __shared__ u16 lds_u16[];

  STAGE_MAP();
  int rlim = cnt - i0;
  int rl = rlim - 1;
  const int* tokp = pair_tok + e * NTOK + i0;
  const u16* pA00 = xb + (size_t)tokp[min(r0, rl)] * DDIM + c0;
  const u16* pA01 = xb + (size_t)tokp[min(r1, rl)] * DDIM + c1;
  const u16* pA10 = xb + (size_t)tokp[min(128 + r0, rl)] * DDIM + c0;
  const u16* pA11 = xb + (size_t)tokp[min(128 + r1, rl)] * DDIM + c1;
  const u16* wbb = W1T + (size_t)e * HDIM * DDIM + (size_t)(p0 + n0) * DDIM;
  const u16* pB00 = wbb + (size_t)r0 * DDIM + c0;
  const u16* pB01 = wbb + (size_t)r1 * DDIM + c1;
  const u16* pB10 = wbb + (size_t)(128 + r0) * DDIM + c0;
  const u16* pB11 = wbb + (size_t)(128 + r1) * DDIM + c1;

  f32x4 acc[8][4] = {};
  GEMM_MAINLOOP(DDIM / 64);

  int ob = offsets[e];
  float bb[4];
#pragma unroll
  for (int nt = 0; nt < 4; ++nt)
    bb[nt] = b1[(size_t)e * HDIM + p0 + n0 + wn * 64 + nt * 16 + ln];
#pragma unroll
  for (int mt = 0; mt < 8; ++mt) {
#pragma unroll
    for (int rr = 0; rr < 4; ++rr) {
      int row = wm * 128 + mt * 16 + q * 4 + rr;
      if (row < rlim) {
        u16* hrow = h + (size_t)(ob + i0 + row) * hp + n0 + wn * 64;
#pragma unroll
        for (int nt = 0; nt < 4; ++nt)
          hrow[nt * 16 + ln] = f2b(fmaxf(acc[mt][nt][rr] + bb[nt], 0.f));
      }
    }
  }
}

// ---------------- grouped GEMM2: y[slot] (+)= h @ W2T[e]^T (+ b2[e]) --------
__global__ __launch_bounds__(512, 2) void gemm2_kernel(
    const u16* __restrict__ h, const u16* __restrict__ W2T,
    const float* __restrict__ b2v, const int* __restrict__ counts,
    const int* __restrict__ offsets, float* __restrict__ y,
    int hp, int p0, int first)
{
  int e = blockIdx.x;
  int cnt = counts[e];
  int i0 = blockIdx.z * 256;
  if (i0 >= cnt) return;
  int n0 = blockIdx.y * 256;
  extern __shared__ u16 lds_u16[];

  STAGE_MAP();
  int rlim = cnt - i0;
  int rl = rlim - 1;
  int rbase = offsets[e] + i0;
  const u16* pA00 = h + (size_t)(rbase + min(r0, rl)) * hp + c0;
  const u16* pA01 = h + (size_t)(rbase + min(r1, rl)) * hp + c1;
  const u16* pA10 = h + (size_t)(rbase + min(128 + r0, rl)) * hp + c0;
  const u16* pA11 = h + (size_t)(rbase + min(128 + r1, rl)) * hp + c1;
  const u16* wbb = W2T + (size_t)e * DDIM * HDIM + (size_t)n0 * HDIM + p0;
  const u16* pB00 = wbb + (size_t)r0 * HDIM + c0;
  const u16* pB01 = wbb + (size_t)r1 * HDIM + c1;
  const u16* pB10 = wbb + (size_t)(128 + r0) * HDIM + c0;
  const u16* pB11 = wbb + (size_t)(128 + r1) * HDIM + c1;

  f32x4 acc[8][4] = {};
  int nk = hp >> 6;
  GEMM_MAINLOOP(nk);

  float bb[4];
#pragma unroll
  for (int nt = 0; nt < 4; ++nt)
    bb[nt] = first ? b2v[(size_t)e * DDIM + n0 + wn * 64 + nt * 16 + ln] : 0.f;
#pragma unroll
  for (int mt = 0; mt < 8; ++mt) {
#pragma unroll
    for (int rr = 0; rr < 4; ++rr) {
      int row = wm * 128 + mt * 16 + q * 4 + rr;
      if (row < rlim) {
        float* yr = y + (size_t)(rbase + row) * DDIM + n0 + wn * 64;
#pragma unroll
        for (int nt = 0; nt < 4; ++nt) {
          float v = acc[mt][nt][rr] + bb[nt];
          if (first) yr[nt * 16 + ln] = v;
          else       yr[nt * 16 + ln] += v;
        }
      }
    }
  }
}

// ---------------- combine: out[tok] = w1*y[slot1] + w2*y[slot2] -------------
__global__ __launch_bounds__(256) void combine_kernel(
    const float* __restrict__ y, const int* __restrict__ tok_ep,
    const float* __restrict__ pair_w, const int* __restrict__ offsets,
    float* __restrict__ out)
{
  int tok = blockIdx.x;
  int ep1 = tok_ep[2 * tok + 0];
  int ep2 = tok_ep[2 * tok + 1];
  int e1 = ep1 >> 16, p1 = ep1 & 0xffff;
  int e2 = ep2 >> 16, p2 = ep2 & 0xffff;
  float w1 = pair_w[e1 * NTOK + p1];
  float w2 = pair_w[e2 * NTOK + p2];
  const float* r1 = y + (size_t)(offsets[e1] + p1) * DDIM;
  const float* r2 = y + (size_t)(offsets[e2] + p2) * DDIM;
  int c = threadIdx.x * 4;
  float4 a = *(const float4*)(r1 + c);
  float4 b = *(const float4*)(r2 + c);
  float4 o;
  o.x = w1 * a.x + w2 * b.x;
  o.y = w1 * a.y + w2 * b.y;
  o.z = w1 * a.z + w2 * b.z;
  o.w = w1 * a.w + w2 * b.w;
  *(float4*)(out + (size_t)tok * DDIM + c) = o;
}

// ---------------- host launch ------------------------------------------------
extern "C" void kernel_launch(void* const* d_in, const int* in_sizes, int n_in,
                              void* d_out, int out_size, void* d_ws, size_t ws_size,
                              hipStream_t stream)
{
  const float* x  = (const float*)d_in[0];
  const float* Wg = (const float*)d_in[1];
  const float* bg = (const float*)d_in[2];
  const float* W1 = (const float*)d_in[3];
  const float* b1 = (const float*)d_in[4];
  const float* W2 = (const float*)d_in[5];
  const float* b2 = (const float*)d_in[6];
  float* out = (float*)d_out;

  char* ws = (char*)d_ws;
  int*   counts   = (int*)(ws + 0);
  int*   offsets  = (int*)(ws + 64);
  int*   tok_ep   = (int*)(ws + 128);
  int*   pair_tok = (int*)(ws + 128 + 65536);
  float* pair_w   = (float*)(ws + 128 + 65536 + 262144);
  u16*   xb  = (u16*)(ws + 589952);
  u16*   W1T = (u16*)(ws + 589952 + 16777216);
  u16*   W2T = (u16*)(ws + 589952 + 16777216 + 67108864);
  float* yb  = (float*)(ws + 589952 + 16777216 + 2 * (size_t)67108864);
  u16*   hbuf = (u16*)(ws + 589952 + 16777216 + 3 * (size_t)67108864);
  size_t used_base = 589952 + 16777216 + 3 * (size_t)67108864;

  // largest H-phase width whose h buffer ((16384+128) rows x hp bf16) fits in ws
  int hp = 256;
  const int cands[5] = {4096, 2048, 1024, 512, 256};
  for (int ci = 0; ci < 5; ++ci) {
    if (used_base + (size_t)16512 * cands[ci] * 2 <= ws_size) { hp = cands[ci]; break; }
  }

  hipFuncSetAttribute((const void*)gemm1_kernel,
                      hipFuncAttributeMaxDynamicSharedMemorySize, 131072);
  hipFuncSetAttribute((const void*)gemm2_kernel,
                      hipFuncAttributeMaxDynamicSharedMemorySize, 131072);

  hipMemsetAsync(counts, 0, 64, stream);
  convert_x_kernel<<<NTOK * DDIM / 2048, 256, 0, stream>>>(x, xb);
  // W1 [E][D][H] -> W1T [E][H][D]
  transpose_kernel<<<dim3(HDIM / 64, DDIM / 64, NEXP), 256, 0, stream>>>(W1, W1T, DDIM, HDIM);
  // W2 [E][H][D] -> W2T [E][D][H]
  transpose_kernel<<<dim3(DDIM / 64, HDIM / 64, NEXP), 256, 0, stream>>>(W2, W2T, HDIM, DDIM);
  gate_kernel<<<NTOK / 4, 256, 0, stream>>>(x, Wg, bg, counts, pair_tok, pair_w, tok_ep);
  offsets_kernel<<<1, 64, 0, stream>>>(counts, offsets);
  for (int p0 = 0; p0 < HDIM; p0 += hp) {
    gemm1_kernel<<<dim3(NEXP, hp / 256, 32), 512, 131072, stream>>>(
        xb, W1T, b1, counts, offsets, pair_tok, hbuf, hp, p0);
    gemm2_kernel<<<dim3(NEXP, DDIM / 256, 32), 512, 131072, stream>>>(
        hbuf, W2T, b2, counts, offsets, yb, hp, p0, p0 == 0 ? 1 : 0);
  }
  combine_kernel<<<NTOK, 256, 0, stream>>>(yb, tok_ep, pair_w, offsets, out);
}

// Round 5
// 839.211 us; speedup vs baseline: 1.2094x; 1.1246x over previous
//
#include <hip/hip_runtime.h>

typedef unsigned short u16;
typedef __attribute__((ext_vector_type(8))) short bf16x8;
typedef __attribute__((ext_vector_type(8))) unsigned short u16x8;
typedef __attribute__((ext_vector_type(4))) float f32x4;

#define NTOK 8192
#define DDIM 1024
#define HDIM 4096
#define NEXP 8

typedef __attribute__((address_space(1))) const void gvoid;
typedef __attribute__((address_space(3))) void lvoid;

__device__ __forceinline__ u16 f2b(float f) {
  unsigned u = __float_as_uint(f);
  u += 0x7fffu + ((u >> 16) & 1u);   // RNE
  return (u16)(u >> 16);
}
__device__ __forceinline__ void glds16(const void* g, void* l) {
  __builtin_amdgcn_global_load_lds((gvoid*)g, (lvoid*)l, 16, 0, 0);
}

// ---------------- pre-pass: x fp32 -> bf16 ----------------------------------
__global__ void convert_x_kernel(const float* __restrict__ src, u16* __restrict__ dst) {
  size_t i = ((size_t)blockIdx.x * 256 + threadIdx.x) * 8;
  float4 a = *(const float4*)(src + i);
  float4 b = *(const float4*)(src + i + 4);
  u16x8 o;
  o[0] = f2b(a.x); o[1] = f2b(a.y); o[2] = f2b(a.z); o[3] = f2b(a.w);
  o[4] = f2b(b.x); o[5] = f2b(b.y); o[6] = f2b(b.z); o[7] = f2b(b.w);
  *(u16x8*)(dst + i) = o;
}

// ---------------- pre-pass: [R][C] fp32 -> [C][R] bf16 (per expert) ---------
__global__ void transpose_kernel(const float* __restrict__ src, u16* __restrict__ dst,
                                 int R, int C) {
  int e = blockIdx.z;
  src += (size_t)e * R * C;
  dst += (size_t)e * R * C;
  int r0 = blockIdx.y * 64, c0 = blockIdx.x * 64;
  __shared__ u16 T[64][68];   // row stride 136 B: 8B-aligned, 2-way bank alias (free)
  int t = threadIdx.x;
  int rr = t >> 4, cc = (t & 15) * 4;
#pragma unroll
  for (int i = 0; i < 4; ++i) {
    int r = i * 16 + rr;
    float4 v = *(const float4*)(src + (size_t)(r0 + r) * C + c0 + cc);
    T[cc + 0][r] = f2b(v.x);
    T[cc + 1][r] = f2b(v.y);
    T[cc + 2][r] = f2b(v.z);
    T[cc + 3][r] = f2b(v.w);
  }
  __syncthreads();
#pragma unroll
  for (int i = 0; i < 4; ++i) {
    int c = i * 16 + rr;
    ushort4 o = *(const ushort4*)&T[c][cc];
    *(ushort4*)(dst + (size_t)(c0 + c) * R + r0 + cc) = o;
  }
}

// ---------------- gating: softmax over 8 experts, top-2, bucket by expert ----
// counts_pad: expert e's counter lives at counts_pad[e*32] -> own 128B line,
// so the 16384 device atomics form 8 parallel chains instead of one.
__global__ void gate_kernel(const float* __restrict__ x, const float* __restrict__ Wg,
                            const float* __restrict__ bg, int* __restrict__ counts_pad,
                            int* __restrict__ pair_tok, float* __restrict__ pair_w,
                            int* __restrict__ tok_ep)
{
  int lane = threadIdx.x & 63;
  int wave = threadIdx.x >> 6;
  int tok = blockIdx.x * 4 + wave;
  const float* xr = x + (size_t)tok * DDIM + lane * 16;
  float acc[NEXP];
#pragma unroll
  for (int e = 0; e < NEXP; ++e) acc[e] = 0.f;
#pragma unroll
  for (int j = 0; j < 16; ++j) {
    float xf = xr[j];
    const float* wr = Wg + (size_t)(lane * 16 + j) * NEXP;
    float4 wa = *(const float4*)(wr);
    float4 wb = *(const float4*)(wr + 4);
    acc[0] = fmaf(xf, wa.x, acc[0]);
    acc[1] = fmaf(xf, wa.y, acc[1]);
    acc[2] = fmaf(xf, wa.z, acc[2]);
    acc[3] = fmaf(xf, wa.w, acc[3]);
    acc[4] = fmaf(xf, wb.x, acc[4]);
    acc[5] = fmaf(xf, wb.y, acc[5]);
    acc[6] = fmaf(xf, wb.z, acc[6]);
    acc[7] = fmaf(xf, wb.w, acc[7]);
  }
#pragma unroll
  for (int off = 32; off > 0; off >>= 1) {
#pragma unroll
    for (int e = 0; e < NEXP; ++e) acc[e] += __shfl_xor(acc[e], off, 64);
  }
  if (lane == 0) {
    float l[NEXP];
    float mx = -3.4e38f;
#pragma unroll
    for (int e = 0; e < NEXP; ++e) { l[e] = acc[e] + bg[e]; mx = fmaxf(mx, l[e]); }
    float s = 0.f;
#pragma unroll
    for (int e = 0; e < NEXP; ++e) { l[e] = __expf(l[e] - mx); s += l[e]; }
    float inv = 1.f / s;
    float v1 = -1.f; int i1 = 0;
#pragma unroll
    for (int e = 0; e < NEXP; ++e) { if (l[e] > v1) { v1 = l[e]; i1 = e; } }
    float v2 = -1.f; int i2 = 0;
#pragma unroll
    for (int e = 0; e < NEXP; ++e) { if (e != i1 && l[e] > v2) { v2 = l[e]; i2 = e; } }
    int p1 = atomicAdd(&counts_pad[i1 * 32], 1);
    pair_tok[i1 * NTOK + p1] = tok;
    pair_w[i1 * NTOK + p1] = v1 * inv;   // raw top-k softmax prob (not renormalized)
    tok_ep[2 * tok + 0] = (i1 << 16) | p1;
    int p2 = atomicAdd(&counts_pad[i2 * 32], 1);
    pair_tok[i2 * NTOK + p2] = tok;
    pair_w[i2 * NTOK + p2] = v2 * inv;
    tok_ep[2 * tok + 1] = (i2 << 16) | p2;
  }
}

// ---------------- offsets + worklist (tiny, 1 thread) -----------------------
__global__ void offsets_kernel(const int* __restrict__ counts_pad, int* __restrict__ counts,
                               int* __restrict__ offsets, int* __restrict__ tile_e,
                               int* __restrict__ tile_i0, int* __restrict__ ntiles)
{
  if (threadIdx.x == 0) {
    int s = 0;
    for (int e = 0; e < NEXP; ++e) {
      int c = counts_pad[e * 32];
      counts[e] = c; offsets[e] = s; s += c;
    }
    int nt_ = 0;
    for (int e = 0; e < NEXP; ++e)
      for (int i0 = 0; i0 < counts[e]; i0 += 128) { tile_e[nt_] = e; tile_i0[nt_] = i0; nt_++; }
    *ntiles = nt_;
  }
}

// ---------------- shared GEMM helpers (128x128 tile, BK=32, 4 waves) --------
__device__ __forceinline__ void stage4(const u16* xa0, const u16* xa1,
                                       const u16* wb0, const u16* wb1,
                                       u16* Asb, u16* Bsb, int wave, int koff) {
  glds16(xa0 + koff, Asb + wave * 512);
  glds16(xa1 + koff, Asb + 2048 + wave * 512);
  glds16(wb0 + koff, Bsb + wave * 512);
  glds16(wb1 + koff, Bsb + 2048 + wave * 512);
}

__device__ __forceinline__ void mfma_tile(const u16* Asb, const u16* Bsb,
                                          f32x4 (&acc)[4][4],
                                          int wrr, int wc, int ln, int q) {
  bf16x8 af[4], bfr[4];
#pragma unroll
  for (int mt = 0; mt < 4; ++mt)
    af[mt] = *(const bf16x8*)(Asb + (wrr + mt * 16 + ln) * 32 + q * 8);
#pragma unroll
  for (int nt = 0; nt < 4; ++nt)
    bfr[nt] = *(const bf16x8*)(Bsb + (wc + nt * 16 + ln) * 32 + q * 8);
#pragma unroll
  for (int mt = 0; mt < 4; ++mt)
#pragma unroll
    for (int nt = 0; nt < 4; ++nt)
      acc[mt][nt] = __builtin_amdgcn_mfma_f32_16x16x32_bf16(af[mt], bfr[nt], acc[mt][nt], 0, 0, 0);
}

// ---------------- grouped GEMM1: h = relu(gather(xb) @ W1T[e]^T + b1[e]) ----
// grid: (136 worklist tiles, hp/128 cols). 136 % 8 == 0: all col-blocks of one
// row-tile share an XCD (A-panel L2 reuse); tiles spread evenly over XCDs.
__global__ __launch_bounds__(256) void gemm1_kernel(
    const u16* __restrict__ xb, const u16* __restrict__ W1T,
    const float* __restrict__ b1, const int* __restrict__ counts,
    const int* __restrict__ offsets, const int* __restrict__ ntiles,
    const int* __restrict__ tile_e, const int* __restrict__ tile_i0,
    const int* __restrict__ pair_tok, u16* __restrict__ h, int hp, int p0)
{
  int bx = blockIdx.x;
  if (bx >= *ntiles) return;
  int e = tile_e[bx];
  int i0 = tile_i0[bx];
  int cnt = counts[e];
  int n0 = blockIdx.y * 128;

  __shared__ __align__(16) u16 As[2][128 * 32];
  __shared__ __align__(16) u16 Bs[2][128 * 32];

  int t = threadIdx.x;
  int lane = t & 63;
  int wave = t >> 6;
  int rlim = cnt - i0;
  int rl = rlim - 1;

  const int* tokp = pair_tok + e * NTOK + i0;
  int arow = t >> 2;
  int c8 = (t & 3) * 8;
  const u16* xa0 = xb + (size_t)tokp[min(arow, rl)] * DDIM + c8;
  const u16* xa1 = xb + (size_t)tokp[min(arow + 64, rl)] * DDIM + c8;
  const u16* wb0 = W1T + (size_t)e * HDIM * DDIM + (size_t)(p0 + n0 + arow) * DDIM + c8;
  const u16* wb1 = wb0 + (size_t)64 * DDIM;

  f32x4 acc[4][4] = {};
  int wrr = (wave >> 1) * 64;
  int wc = (wave & 1) * 64;
  int ln = lane & 15;
  int q = lane >> 4;

  stage4(xa0, xa1, wb0, wb1, As[0], Bs[0], wave, 0);
  __syncthreads();
  for (int k0 = 0; k0 < DDIM; k0 += 64) {
    stage4(xa0, xa1, wb0, wb1, As[1], Bs[1], wave, k0 + 32);
    __builtin_amdgcn_sched_barrier(0);
    mfma_tile(As[0], Bs[0], acc, wrr, wc, ln, q);
    __syncthreads();
    if (k0 + 64 < DDIM) {
      stage4(xa0, xa1, wb0, wb1, As[0], Bs[0], wave, k0 + 64);
      __builtin_amdgcn_sched_barrier(0);
    }
    mfma_tile(As[1], Bs[1], acc, wrr, wc, ln, q);
    __syncthreads();
  }

  int ob = offsets[e];
  float bb[4];
#pragma unroll
  for (int nt = 0; nt < 4; ++nt)
    bb[nt] = b1[(size_t)e * HDIM + p0 + n0 + wc + nt * 16 + ln];
  size_t hbase = (size_t)(ob + i0) * hp + n0 + wc;
#pragma unroll
  for (int mt = 0; mt < 4; ++mt) {
#pragma unroll
    for (int r = 0; r < 4; ++r) {
      int row = wrr + mt * 16 + q * 4 + r;
      if (row < rlim) {
        u16* hrow = h + hbase + (size_t)row * hp;
#pragma unroll
        for (int nt = 0; nt < 4; ++nt) {
          float v = acc[mt][nt][r] + bb[nt];
          hrow[nt * 16 + ln] = f2b(fmaxf(v, 0.f));
        }
      }
    }
  }
}

// ---------------- grouped GEMM2: y[slot] (+)= h @ W2T[e]^T (+ b2[e]) --------
__global__ __launch_bounds__(256) void gemm2_kernel(
    const u16* __restrict__ h, const u16* __restrict__ W2T,
    const float* __restrict__ b2v, const int* __restrict__ counts,
    const int* __restrict__ offsets, const int* __restrict__ ntiles,
    const int* __restrict__ tile_e, const int* __restrict__ tile_i0,
    float* __restrict__ y, int hp, int p0, int first)
{
  int bx = blockIdx.x;
  if (bx >= *ntiles) return;
  int e = tile_e[bx];
  int i0 = tile_i0[bx];
  int cnt = counts[e];
  int n0 = blockIdx.y * 128;

  __shared__ __align__(16) u16 As[2][128 * 32];
  __shared__ __align__(16) u16 Bs[2][128 * 32];

  int t = threadIdx.x;
  int lane = t & 63;
  int wave = t >> 6;
  int rlim = cnt - i0;
  int rl = rlim - 1;
  int rbase = offsets[e] + i0;

  int arow = t >> 2;
  int c8 = (t & 3) * 8;
  const u16* xa0 = h + (size_t)(rbase + min(arow, rl)) * hp + c8;
  const u16* xa1 = h + (size_t)(rbase + min(arow + 64, rl)) * hp + c8;
  const u16* wb0 = W2T + (size_t)e * DDIM * HDIM + (size_t)(n0 + arow) * HDIM + p0 + c8;
  const u16* wb1 = wb0 + (size_t)64 * HDIM;

  f32x4 acc[4][4] = {};
  int wrr = (wave >> 1) * 64;
  int wc = (wave & 1) * 64;
  int ln = lane & 15;
  int q = lane >> 4;

  stage4(xa0, xa1, wb0, wb1, As[0], Bs[0], wave, 0);
  __syncthreads();
  for (int k0 = 0; k0 < hp; k0 += 64) {
    stage4(xa0, xa1, wb0, wb1, As[1], Bs[1], wave, k0 + 32);
    __builtin_amdgcn_sched_barrier(0);
    mfma_tile(As[0], Bs[0], acc, wrr, wc, ln, q);
    __syncthreads();
    if (k0 + 64 < hp) {
      stage4(xa0, xa1, wb0, wb1, As[0], Bs[0], wave, k0 + 64);
      __builtin_amdgcn_sched_barrier(0);
    }
    mfma_tile(As[1], Bs[1], acc, wrr, wc, ln, q);
    __syncthreads();
  }

  float bb[4];
#pragma unroll
  for (int nt = 0; nt < 4; ++nt)
    bb[nt] = first ? b2v[(size_t)e * DDIM + n0 + wc + nt * 16 + ln] : 0.f;
#pragma unroll
  for (int mt = 0; mt < 4; ++mt) {
#pragma unroll
    for (int r = 0; r < 4; ++r) {
      int row = wrr + mt * 16 + q * 4 + r;
      if (row < rlim) {
        float* yr = y + (size_t)(rbase + row) * DDIM + n0 + wc;
#pragma unroll
        for (int nt = 0; nt < 4; ++nt) {
          float v = acc[mt][nt][r] + bb[nt];
          if (first) yr[nt * 16 + ln] = v;
          else       yr[nt * 16 + ln] += v;
        }
      }
    }
  }
}

// ---------------- combine: out[tok] = w1*y[slot1] + w2*y[slot2] -------------
__global__ __launch_bounds__(256) void combine_kernel(
    const float* __restrict__ y, const int* __restrict__ tok_ep,
    const float* __restrict__ pair_w, const int* __restrict__ offsets,
    float* __restrict__ out)
{
  int tok = blockIdx.x;
  int ep1 = tok_ep[2 * tok + 0];
  int ep2 = tok_ep[2 * tok + 1];
  int e1 = ep1 >> 16, p1 = ep1 & 0xffff;
  int e2 = ep2 >> 16, p2 = ep2 & 0xffff;
  float w1 = pair_w[e1 * NTOK + p1];
  float w2 = pair_w[e2 * NTOK + p2];
  const float* r1 = y + (size_t)(offsets[e1] + p1) * DDIM;
  const float* r2 = y + (size_t)(offsets[e2] + p2) * DDIM;
  int c = threadIdx.x * 4;
  float4 a = *(const float4*)(r1 + c);
  float4 b = *(const float4*)(r2 + c);
  float4 o;
  o.x = w1 * a.x + w2 * b.x;
  o.y = w1 * a.y + w2 * b.y;
  o.z = w1 * a.z + w2 * b.z;
  o.w = w1 * a.w + w2 * b.w;
  *(float4*)(out + (size_t)tok * DDIM + c) = o;
}

// ---------------- host launch ------------------------------------------------
extern "C" void kernel_launch(void* const* d_in, const int* in_sizes, int n_in,
                              void* d_out, int out_size, void* d_ws, size_t ws_size,
                              hipStream_t stream)
{
  const float* x  = (const float*)d_in[0];
  const float* Wg = (const float*)d_in[1];
  const float* bg = (const float*)d_in[2];
  const float* W1 = (const float*)d_in[3];
  const float* b1 = (const float*)d_in[4];
  const float* W2 = (const float*)d_in[5];
  const float* b2 = (const float*)d_in[6];
  float* out = (float*)d_out;

  char* ws = (char*)d_ws;
  int*   counts_pad = (int*)(ws + 0);                      // 8 counters, 128B apart
  int*   counts     = (int*)(ws + 1024);
  int*   offsets    = (int*)(ws + 1056);
  int*   ntiles     = (int*)(ws + 1088);
  int*   tile_e     = (int*)(ws + 1152);                   // <=136 entries
  int*   tile_i0    = (int*)(ws + 2176);
  int*   tok_ep     = (int*)(ws + 4096);                   // 64 KiB
  int*   pair_tok   = (int*)(ws + 69632);                  // 256 KiB
  float* pair_w     = (float*)(ws + 331776);               // 256 KiB
  u16*   xb  = (u16*)(ws + 593920);                                // 16.78 MB
  u16*   W1T = (u16*)(ws + 593920 + 16777216);                     // 67.1 MB
  u16*   W2T = (u16*)(ws + 593920 + 16777216 + 67108864);          // 67.1 MB
  float* yb  = (float*)(ws + 593920 + 16777216 + 2 * (size_t)67108864);
  u16*   hbuf = (u16*)(ws + 593920 + 16777216 + 3 * (size_t)67108864);
  size_t used_base = 593920 + 16777216 + 3 * (size_t)67108864;

  // largest H-phase width whose h buffer ((16384+128) rows x hp bf16) fits in ws
  int hp = 256;
  const int cands[5] = {4096, 2048, 1024, 512, 256};
  for (int ci = 0; ci < 5; ++ci) {
    if (used_base + (size_t)16512 * cands[ci] * 2 <= ws_size) { hp = cands[ci]; break; }
  }

  hipMemsetAsync(counts_pad, 0, 1024, stream);
  convert_x_kernel<<<NTOK * DDIM / 2048, 256, 0, stream>>>(x, xb);
  // W1 [E][D][H] -> W1T [E][H][D]
  transpose_kernel<<<dim3(HDIM / 64, DDIM / 64, NEXP), 256, 0, stream>>>(W1, W1T, DDIM, HDIM);
  // W2 [E][H][D] -> W2T [E][D][H]
  transpose_kernel<<<dim3(DDIM / 64, HDIM / 64, NEXP), 256, 0, stream>>>(W2, W2T, HDIM, DDIM);
  gate_kernel<<<NTOK / 4, 256, 0, stream>>>(x, Wg, bg, counts_pad, pair_tok, pair_w, tok_ep);
  offsets_kernel<<<1, 64, 0, stream>>>(counts_pad, counts, offsets, tile_e, tile_i0, ntiles);
  for (int p0 = 0; p0 < HDIM; p0 += hp) {
    gemm1_kernel<<<dim3(136, hp / 128), 256, 0, stream>>>(
        xb, W1T, b1, counts, offsets, ntiles, tile_e, tile_i0, pair_tok, hbuf, hp, p0);
    gemm2_kernel<<<dim3(136, DDIM / 128), 256, 0, stream>>>(
        hbuf, W2T, b2, counts, offsets, ntiles, tile_e, tile_i0, yb, hp, p0, p0 == 0 ? 1 : 0);
  }
  combine_kernel<<<NTOK, 256, 0, stream>>>(yb, tok_ep, pair_w, offsets, out);
}